// Round 5
// baseline (216.833 us; speedup 1.0000x reference)
//
#include <hip/hip_runtime.h>
#include <hip/hip_bf16.h>

constexpr int FDIM  = 128;
constexpr int BSH   = 5;      // 32 nodes per bucket
constexpr int BWD   = 32;
constexpr int NBMAX = 2048;   // supports N <= 65536 (N = 50000)
constexpr int CAP   = 3072;   // per-bucket LDS record capacity in k_agg8 (incl. padding)
constexpr int CAPB  = 2048;   // fixed per-bucket global record capacity (mean 512, sd ~23)
constexpr int SAB   = 16;     // buckets per scanA block

typedef __attribute__((ext_vector_type(8))) short bf16x8;   // 8 bf16 = 4 VGPRs
typedef __attribute__((ext_vector_type(4))) float f32x4;
typedef __attribute__((ext_vector_type(2))) float f32x2;

static __device__ __forceinline__ ushort f2bf(float f){
    union { float f; unsigned u; } v; v.f = f;
    unsigned r = v.u + 0x7fffu + ((v.u >> 16) & 1u);   // RNE
    return (ushort)(r >> 16);
}
static __device__ __forceinline__ unsigned char f2fp8(float f){
    return (unsigned char)(__builtin_amdgcn_cvt_pk_fp8_f32(f, f, 0, false) & 0xff);
}

// ---------------- pass 1 (fused): bucket histogram | x cast | weight swizzle | dummy-row zero ----------------

__global__ __launch_bounds__(256) void k_pass1(
    const int* __restrict__ dst, int* __restrict__ hist,
    int E, int ESB, int NB, int SB,
    const float* __restrict__ xsrc, ushort* __restrict__ xb,
    unsigned char* __restrict__ x8, unsigned char* __restrict__ h8, int nx, int gC,
    const float* __restrict__ W1_l, const float* __restrict__ W1_r,
    const float* __restrict__ Wl1,
    const float* __restrict__ W2_l, const float* __restrict__ W2_r,
    ushort* __restrict__ Wf1, ushort* __restrict__ Wfm, ushort* __restrict__ Wf2)
{
    const int b = (int)blockIdx.x;
    const int t = (int)threadIdx.x;
    if (b < SB){
        __shared__ int lh[NBMAX];
        for (int i = t; i < NB; i += 256) lh[i] = 0;
        __syncthreads();
        const int e1 = min(E, (b + 1) * ESB);
        for (int e = b * ESB + t; e < e1; e += 256)
            atomicAdd(&lh[dst[e] >> BSH], 1);                 // LDS atomic only
        __syncthreads();
        for (int i = t; i < NB; i += 256) hist[(size_t)b * NB + i] = lh[i];
    } else if (b < SB + gC){
        int i4 = ((b - SB) * 256 + t) * 4;
        if (i4 < nx){
            float4 v = *(const float4*)(xsrc + i4);
            ushort4 o; o.x = f2bf(v.x); o.y = f2bf(v.y); o.z = f2bf(v.z); o.w = f2bf(v.w);
            *(ushort4*)(xb + i4) = o;
            unsigned w = __builtin_amdgcn_cvt_pk_fp8_f32(v.x, v.y, 0, false);
            w = (unsigned)__builtin_amdgcn_cvt_pk_fp8_f32(v.z, v.w, (int)w, true);
            *(unsigned*)(x8 + i4) = w;
        }
    } else if (b < SB + gC + 320){
        // weight swizzle into MFMA fragment order:
        // Wf[((nt*8+kt)*64 + lane)*8 + j] = W[nt*16 + (lane&15)][kt*32 + (lane>>4)*8 + j]
        int i = (b - SB - gC) * 256 + t;                      // 320 blocks -> 81920 ushorts
        int f; ushort* dstp; int which;
        if (i < 32768){ f = i;          dstp = Wf1; which = 0; }
        else if (i < 65536){ f = i - 32768; dstp = Wfm; which = 1; }
        else { f = i - 65536; dstp = Wf2; which = 2; }
        int j    = f & 7;
        int lane = (f >> 3) & 63;
        int q    = f >> 9;
        int kt = q & 7, nt = q >> 3;
        int n = nt * 16 + (lane & 15);
        int k = kt * 32 + (lane >> 4) * 8 + j;
        float v;
        if (which == 0)      v = (k < 128) ? W1_l[(size_t)n * 128 + k] : W1_r[(size_t)n * 128 + (k - 128)];
        else if (which == 1) v = Wl1[(size_t)n * 256 + k];
        else                 v = (k < 128) ? W2_l[(size_t)n * 128 + k] : W2_r[(size_t)n * 128 + (k - 128)];
        dstp[f] = f2bf(v);
    } else {
        // zero the dummy row (index N) of both fp8 feature buffers
        if (t < 8)       *(uint4*)(x8 + (size_t)nx + t*16)      = make_uint4(0,0,0,0);
        else if (t < 16) *(uint4*)(h8 + (size_t)nx + (t-8)*16)  = make_uint4(0,0,0,0);
    }
}

// ---------------- scanA (tiled): per bucket, exclusive scan of hist over 256 scatter blocks ----------------

__global__ __launch_bounds__(256) void k_scanA(const int* __restrict__ hist, int* __restrict__ base,
                                               int* __restrict__ bktcnt, int NB)
{
    __shared__ int T[256][SAB + 1];
    __shared__ int psum[16][SAB];
    const int t = (int)threadIdx.x;
    const int b0 = (int)blockIdx.x * SAB;
    const int cl = t & (SAB - 1);
    const int rt = t >> 4;
    for (int it = 0; it < 16; it++){
        const int row = it * 16 + rt;
        T[row][cl] = (b0 + cl < NB) ? hist[(size_t)row * NB + b0 + cl] : 0;
    }
    __syncthreads();
    const int c = t & (SAB - 1), seg = t >> 4;
    int s = 0;
    #pragma unroll
    for (int i = 0; i < 16; i++) s += T[seg * 16 + i][c];
    psum[seg][c] = s;
    __syncthreads();
    int off = 0;
    #pragma unroll
    for (int s2 = 0; s2 < 16; s2++){ int v = psum[s2][c]; if (s2 < seg) off += v; }
    int run = off;
    #pragma unroll
    for (int i = 0; i < 16; i++){
        const int idx = seg * 16 + i;
        const int v = T[idx][c];
        T[idx][c] = run;
        run += v;
    }
    if (seg == 15 && b0 + c < NB) bktcnt[b0 + c] = run;
    __syncthreads();
    for (int it = 0; it < 16; it++){
        const int row = it * 16 + rt;
        if (b0 + cl < NB) base[(size_t)row * NB + b0 + cl] = T[row][cl];
    }
}

// ---------------- scatter: bucket-sort edges; rec = (dloc<<24) | src*FDIM (premultiplied payload) ----------------
__global__ __launch_bounds__(256) void k_scatter(
    const int* __restrict__ dst, const int* __restrict__ src,
    const int* __restrict__ base,
    unsigned* __restrict__ recs, int E, int ESB, int NB)
{
    __shared__ int gbase[NBMAX];
    __shared__ int h2[NBMAX];
    const int h = (int)blockIdx.x;
    for (int i = (int)threadIdx.x; i < NB; i += 256){
        gbase[i] = base[(size_t)h * NB + i];
        h2[i] = 0;
    }
    __syncthreads();
    const int e1 = min(E, (h + 1) * ESB);
    for (int e = h * ESB + (int)threadIdx.x; e < e1; e += 256){
        const int d = dst[e], s = src[e];
        const int bk = d >> BSH;
        const int r  = atomicAdd(&h2[bk], 1);     // LDS atomic
        const int pos = gbase[bk] + r;
        if (pos < CAPB)                           // overflow edges handled by agg fallback
            recs[(size_t)bk * CAPB + pos] = ((unsigned)(d & (BWD - 1)) << 24) | ((unsigned)s * FDIM);
    }
}

// ---------------- mean aggregation over fp8 features ----------------
// One block per 32-node bucket. Counting-sort to LDS (segments padded to x4 with dummy recs ->
// maskless gather). Each wave processes TWO nodes interleaved: 8 gather loads in flight.

__global__ __launch_bounds__(256) void k_agg8(
    const unsigned char* __restrict__ feat8, const unsigned* __restrict__ recs,
    const int* __restrict__ bktcnt,
    const int* __restrict__ dstg, const int* __restrict__ srcg, int E,
    ushort* __restrict__ agg, int N)
{
    __shared__ unsigned lrec[CAP];
    __shared__ int ldeg[BWD], loffp[BWD + 1], lpos[BWD];

    const int b = (int)blockIdx.x;
    const int t = (int)threadIdx.x;
    const int wave = t >> 6, lane = t & 63;
    const int grp = lane >> 4, sub = lane & 15;
    const int subo = sub * 8;
    const int cnt = bktcnt[b];
    const unsigned* brec = recs + (size_t)b * CAPB;

    if (t < BWD){ ldeg[t] = 0; lpos[t] = 0; }
    __syncthreads();

    auto writeout = [&](int node, int d, f32x2 a01, f32x2 a23, f32x2 a45, f32x2 a67){
        float v0=a01.x,v1=a01.y,v2=a23.x,v3=a23.y,v4=a45.x,v5=a45.y,v6=a67.x,v7=a67.y;
        v0 += __shfl_xor(v0,16); v1 += __shfl_xor(v1,16); v2 += __shfl_xor(v2,16); v3 += __shfl_xor(v3,16);
        v4 += __shfl_xor(v4,16); v5 += __shfl_xor(v5,16); v6 += __shfl_xor(v6,16); v7 += __shfl_xor(v7,16);
        v0 += __shfl_xor(v0,32); v1 += __shfl_xor(v1,32); v2 += __shfl_xor(v2,32); v3 += __shfl_xor(v3,32);
        v4 += __shfl_xor(v4,32); v5 += __shfl_xor(v5,32); v6 += __shfl_xor(v6,32); v7 += __shfl_xor(v7,32);
        if (grp == 0){
            float inv = 1.f / (float)(d > 1 ? d : 1);
            uint4 r;
            r.x = (unsigned)f2bf(v0*inv) | ((unsigned)f2bf(v1*inv) << 16);
            r.y = (unsigned)f2bf(v2*inv) | ((unsigned)f2bf(v3*inv) << 16);
            r.z = (unsigned)f2bf(v4*inv) | ((unsigned)f2bf(v5*inv) << 16);
            r.w = (unsigned)f2bf(v6*inv) | ((unsigned)f2bf(v7*inv) << 16);
            *(uint4*)(agg + (size_t)node*FDIM + subo) = r;
        }
    };

    if (cnt <= CAPB){
        // ---- counting sort with per-node padding to x4 ----
        for (int i = t; i < cnt; i += 256) atomicAdd(&ldeg[(brec[i] >> 24) & (BWD-1)], 1);
        __syncthreads();
        if (t == 0){
            int r = 0;
            #pragma unroll
            for (int j = 0; j < BWD; j++){ loffp[j] = r; r += (ldeg[j] + 3) & ~3; }
            loffp[BWD] = r;               // <= cnt + 96 < CAP always
        }
        __syncthreads();
        for (int i = t; i < cnt; i += 256){
            const unsigned rec = brec[i];
            const int dl = (rec >> 24) & (BWD-1);
            lrec[loffp[dl] + atomicAdd(&lpos[dl], 1)] = rec;
        }
        if (t < BWD){                     // pad slots -> dummy row N (zeroed fp8)
            const int de = (ldeg[t] + 3) & ~3;
            for (int r = ldeg[t]; r < de; r++) lrec[loffp[t] + r] = (unsigned)N * FDIM;
        }
        __syncthreads();

        // ---- two-node interleaved maskless gather (8 loads in flight per wave) ----
        for (int np = wave*2; np < BWD; np += 8){
            const int nodeA = b*BWD + np, nodeB = nodeA + 1;
            const bool vA = nodeA < N, vB = nodeB < N;
            const int oA = loffp[np],   dA = vA ? ldeg[np]   : 0;
            const int oB = loffp[np+1], dB = vB ? ldeg[np+1] : 0;
            const int itA = (dA + 3) >> 2, itB = (dB + 3) >> 2;

            f32x2 A01{0.f,0.f}, A23{0.f,0.f}, A45{0.f,0.f}, A67{0.f,0.f};
            f32x2 B01{0.f,0.f}, B23{0.f,0.f}, B45{0.f,0.f}, B67{0.f,0.f};
            auto accA = [&](uint2 raw){
                A01 += __builtin_amdgcn_cvt_pk_f32_fp8((int)raw.x, false);
                A23 += __builtin_amdgcn_cvt_pk_f32_fp8((int)raw.x, true);
                A45 += __builtin_amdgcn_cvt_pk_f32_fp8((int)raw.y, false);
                A67 += __builtin_amdgcn_cvt_pk_f32_fp8((int)raw.y, true);
            };
            auto accB = [&](uint2 raw){
                B01 += __builtin_amdgcn_cvt_pk_f32_fp8((int)raw.x, false);
                B23 += __builtin_amdgcn_cvt_pk_f32_fp8((int)raw.x, true);
                B45 += __builtin_amdgcn_cvt_pk_f32_fp8((int)raw.y, false);
                B67 += __builtin_amdgcn_cvt_pk_f32_fp8((int)raw.y, true);
            };

            const int jc = min(itA, itB);
            int j = 0;
            for (; j + 2 <= jc; j += 2){
                const unsigned ra0 = lrec[oA + (j+0)*4 + grp];
                const unsigned rb0 = lrec[oB + (j+0)*4 + grp];
                const unsigned ra1 = lrec[oA + (j+1)*4 + grp];
                const unsigned rb1 = lrec[oB + (j+1)*4 + grp];
                uint2 va0 = *(const uint2*)(feat8 + (ra0 & 0xFFFFFFu) + subo);
                uint2 vb0 = *(const uint2*)(feat8 + (rb0 & 0xFFFFFFu) + subo);
                uint2 va1 = *(const uint2*)(feat8 + (ra1 & 0xFFFFFFu) + subo);
                uint2 vb1 = *(const uint2*)(feat8 + (rb1 & 0xFFFFFFu) + subo);
                accA(va0); accB(vb0); accA(va1); accB(vb1);
            }
            for (; j < jc; j++){
                const unsigned ra = lrec[oA + j*4 + grp];
                const unsigned rb = lrec[oB + j*4 + grp];
                uint2 va = *(const uint2*)(feat8 + (ra & 0xFFFFFFu) + subo);
                uint2 vb = *(const uint2*)(feat8 + (rb & 0xFFFFFFu) + subo);
                accA(va); accB(vb);
            }
            for (int ja = jc; ja < itA; ja++){
                const unsigned ra = lrec[oA + ja*4 + grp];
                uint2 va = *(const uint2*)(feat8 + (ra & 0xFFFFFFu) + subo);
                accA(va);
            }
            for (int jb = jc; jb < itB; jb++){
                const unsigned rb = lrec[oB + jb*4 + grp];
                uint2 vb = *(const uint2*)(feat8 + (rb & 0xFFFFFFu) + subo);
                accB(vb);
            }
            if (vA) writeout(nodeA, dA, A01, A23, A45, A67);
            if (vB) writeout(nodeB, dB, B01, B23, B45, B67);
        }
    } else {
        // ---- fallback (bucket overflow; O(E) rescan of the raw edge list; never triggered here) ----
        for (int nl = wave; nl < BWD; nl += 4){
            const int node = b*BWD + nl;
            if (node >= N) break;
            f32x2 a01{0.f,0.f}, a23{0.f,0.f}, a45{0.f,0.f}, a67{0.f,0.f};
            int d = 0;
            for (int e = 0; e < E; e++){
                if (dstg[e] == node){
                    d++;
                    if (grp == 0){
                        uint2 raw = *(const uint2*)(feat8 + (size_t)srcg[e]*FDIM + subo);
                        a01 += __builtin_amdgcn_cvt_pk_f32_fp8((int)raw.x, false);
                        a23 += __builtin_amdgcn_cvt_pk_f32_fp8((int)raw.x, true);
                        a45 += __builtin_amdgcn_cvt_pk_f32_fp8((int)raw.y, false);
                        a67 += __builtin_amdgcn_cvt_pk_f32_fp8((int)raw.y, true);
                    }
                }
            }
            writeout(node, d, a01, a23, a45, a67);
        }
    }
}

// ---------------- fused lin1 + mid-lin ----------------
// h1 = relu(norm([agg|x] @ W1^T + b1)) never touches HBM; mid: h = relu([x|h1] @ Wl1^T + bl1).
// B-fragments read DIRECTLY from global Wf1/Wfm (L2-resident, 64 KB each; one read feeds 2 tiles).
// h1 tile transposed C-layout -> A-frag layout through per-tile XOR-swizzled LDS (wave-private,
// separate buffer per tile -> no reuse hazard).

__global__ __launch_bounds__(256) void k_lin12(
    const ushort* __restrict__ Agg, const ushort* __restrict__ Xb,
    const ushort* __restrict__ Wf1, const ushort* __restrict__ Wfm,
    const float* __restrict__ b1, const float* __restrict__ bm,
    ushort* __restrict__ hb, unsigned char* __restrict__ h8, int N, int TILES)
{
    __shared__ __align__(16) ushort hT[4][2][2048];   // per-wave, per-tile 16x128 transpose (32 KB)

    const int wave = threadIdx.x >> 6, lane = threadIdx.x & 63;
    const int m = lane & 15, quad = lane >> 4;
    const ushort* W1l = Wf1 + lane*8;                 // frag (nt,kt) at + (nt*8+kt)*512
    const ushort* Wml = Wfm + lane*8;

    const int g  = (int)blockIdx.x*4 + wave;          // 0..2047
    const int t0 = g, t1 = g + 2048;
    const bool has2 = (t1 < TILES);

    // ---- A-frag loads (both tiles) ----
    bf16x8 aA0[4], aX0[4], aA1[4], aX1[4];
    {
        const int r0 = min(t0*16 + m, N-1);
        const ushort* p1 = Agg + (size_t)r0*FDIM + quad*8;
        const ushort* p2 = Xb  + (size_t)r0*FDIM + quad*8;
        #pragma unroll
        for (int c = 0; c < 4; c++){
            aA0[c] = *(const bf16x8*)(p1 + c*32);
            aX0[c] = *(const bf16x8*)(p2 + c*32);
        }
    }
    if (has2){
        const int r1 = min(t1*16 + m, N-1);
        const ushort* p1 = Agg + (size_t)r1*FDIM + quad*8;
        const ushort* p2 = Xb  + (size_t)r1*FDIM + quad*8;
        #pragma unroll
        for (int c = 0; c < 4; c++){
            aA1[c] = *(const bf16x8*)(p1 + c*32);
            aX1[c] = *(const bf16x8*)(p2 + c*32);
        }
    }

    // ---- GEMM1: [agg|x] @ W1^T (B-frag shared across both tiles) ----
    f32x4 acc0[8], acc1[8];
    #pragma unroll
    for (int nt = 0; nt < 8; nt++){ acc0[nt] = f32x4{0.f,0.f,0.f,0.f}; acc1[nt] = f32x4{0.f,0.f,0.f,0.f}; }
    if (has2){
        #pragma unroll
        for (int kt = 0; kt < 8; kt++){
            bf16x8 a0 = (kt < 4) ? aA0[kt] : aX0[kt-4];
            bf16x8 a1 = (kt < 4) ? aA1[kt] : aX1[kt-4];
            #pragma unroll
            for (int nt = 0; nt < 8; nt++){
                bf16x8 w = *(const bf16x8*)(W1l + (nt*8+kt)*512);
                acc0[nt] = __builtin_amdgcn_mfma_f32_16x16x32_bf16(a0, w, acc0[nt], 0, 0, 0);
                acc1[nt] = __builtin_amdgcn_mfma_f32_16x16x32_bf16(a1, w, acc1[nt], 0, 0, 0);
            }
        }
    } else {
        #pragma unroll
        for (int kt = 0; kt < 8; kt++){
            bf16x8 a0 = (kt < 4) ? aA0[kt] : aX0[kt-4];
            #pragma unroll
            for (int nt = 0; nt < 8; nt++){
                bf16x8 w = *(const bf16x8*)(W1l + (nt*8+kt)*512);
                acc0[nt] = __builtin_amdgcn_mfma_f32_16x16x32_bf16(a0, w, acc0[nt], 0, 0, 0);
            }
        }
    }

    // ---- epi1: bias + L2 row-norm + relu ----
    auto epi1 = [&](f32x4* acc){
        #pragma unroll
        for (int nt = 0; nt < 8; nt++){
            float bb = b1[nt*16 + m];
            acc[nt][0]+=bb; acc[nt][1]+=bb; acc[nt][2]+=bb; acc[nt][3]+=bb;
        }
        #pragma unroll
        for (int reg = 0; reg < 4; reg++){
            float ss = 0.f;
            #pragma unroll
            for (int nt = 0; nt < 8; nt++) ss += acc[nt][reg]*acc[nt][reg];
            ss += __shfl_xor(ss,1); ss += __shfl_xor(ss,2); ss += __shfl_xor(ss,4); ss += __shfl_xor(ss,8);
            float invn = 1.f / fmaxf(sqrtf(ss), 1e-12f);
            #pragma unroll
            for (int nt = 0; nt < 8; nt++) acc[nt][reg] = fmaxf(acc[nt][reg]*invn, 0.f);
        }
    };
    // ---- transpose h1 tile (C layout -> A-frag layout) via XOR-swizzled LDS ----
    auto transpose = [&](const f32x4* acc, ushort* hTw, bf16x8* afH){
        #pragma unroll
        for (int nt = 0; nt < 8; nt++)
            #pragma unroll
            for (int reg = 0; reg < 4; reg++){
                const int row = quad*4 + reg;
                hTw[(row*128 + nt*16 + m) ^ ((row & 7) << 3)] = f2bf(acc[nt][reg]);
            }
        #pragma unroll
        for (int c = 0; c < 4; c++)
            afH[c] = *(const bf16x8*)&hTw[(m*128 + quad*8 + c*32) ^ ((m & 7) << 3)];
    };

    bf16x8 aH0[4], aH1[4];
    epi1(acc0);
    transpose(acc0, hT[wave][0], aH0);
    if (has2){
        epi1(acc1);
        transpose(acc1, hT[wave][1], aH1);
    }

    // ---- GEMM2: [x|h1] @ Wl1^T ----
    f32x4 am0[8], am1[8];
    #pragma unroll
    for (int nt = 0; nt < 8; nt++){ am0[nt] = f32x4{0.f,0.f,0.f,0.f}; am1[nt] = f32x4{0.f,0.f,0.f,0.f}; }
    if (has2){
        #pragma unroll
        for (int kt = 0; kt < 8; kt++){
            bf16x8 a0 = (kt < 4) ? aX0[kt] : aH0[kt-4];
            bf16x8 a1 = (kt < 4) ? aX1[kt] : aH1[kt-4];
            #pragma unroll
            for (int nt = 0; nt < 8; nt++){
                bf16x8 w = *(const bf16x8*)(Wml + (nt*8+kt)*512);
                am0[nt] = __builtin_amdgcn_mfma_f32_16x16x32_bf16(a0, w, am0[nt], 0, 0, 0);
                am1[nt] = __builtin_amdgcn_mfma_f32_16x16x32_bf16(a1, w, am1[nt], 0, 0, 0);
            }
        }
    } else {
        #pragma unroll
        for (int kt = 0; kt < 8; kt++){
            bf16x8 a0 = (kt < 4) ? aX0[kt] : aH0[kt-4];
            #pragma unroll
            for (int nt = 0; nt < 8; nt++){
                bf16x8 w = *(const bf16x8*)(Wml + (nt*8+kt)*512);
                am0[nt] = __builtin_amdgcn_mfma_f32_16x16x32_bf16(a0, w, am0[nt], 0, 0, 0);
            }
        }
    }

    // ---- epi-mid: bias + relu, store hb (bf16) + h8 (fp8) ----
    auto epim = [&](int tt, f32x4* acc){
        #pragma unroll
        for (int nt = 0; nt < 8; nt++){
            float bb = bm[nt*16 + m];
            acc[nt][0]=fmaxf(acc[nt][0]+bb,0.f); acc[nt][1]=fmaxf(acc[nt][1]+bb,0.f);
            acc[nt][2]=fmaxf(acc[nt][2]+bb,0.f); acc[nt][3]=fmaxf(acc[nt][3]+bb,0.f);
        }
        #pragma unroll
        for (int reg = 0; reg < 4; reg++){
            const int row = tt*16 + quad*4 + reg;
            if (row < N){
                ushort* o = hb + (size_t)row*FDIM + m;
                unsigned char* o8 = h8 + (size_t)row*FDIM + m;
                #pragma unroll
                for (int nt = 0; nt < 8; nt++){
                    o[nt*16]  = f2bf(acc[nt][reg]);
                    o8[nt*16] = f2fp8(acc[nt][reg]);
                }
            }
        }
    };
    epim(t0, am0);
    if (has2) epim(t1, am1);
}

// ---------------- LDS-weight linear (layer 2) ----------------

template<int NT, bool NORM, bool RELU, bool OUTF32, bool FP8OUT>
__global__ __launch_bounds__(256) void k_lin(
    const ushort* __restrict__ A1, const ushort* __restrict__ A2,
    const ushort* __restrict__ Wf, const float* __restrict__ bias,
    void* __restrict__ outv, unsigned char* __restrict__ out8, int N, int TILES)
{
    __shared__ __align__(16) ushort WS[NT*8*64*8];   // NT*8 KB
    {
        const uint4* wsrc = (const uint4*)Wf;
        uint4* wdst = (uint4*)WS;
        for (int i = threadIdx.x; i < NT*512; i += 256) wdst[i] = wsrc[i];
    }
    __syncthreads();

    const int wave = threadIdx.x >> 6, lane = threadIdx.x & 63;
    const int m = lane & 15, quad = lane >> 4;
    const ushort* WSl = WS + lane*8;    // frag (nt,kt) at WSl + (nt*8+kt)*512

    const int g  = blockIdx.x*4 + wave;          // 0..2047
    const int t0 = g, t1 = g + 2048;
    const bool has2 = (t1 < TILES);

    bf16x8 af0[8], af1[8];
    {
        int r0 = min(t0*16 + m, N-1);
        const ushort* p1 = A1 + (size_t)r0*FDIM + quad*8;
        const ushort* p2 = A2 + (size_t)r0*FDIM + quad*8;
        #pragma unroll
        for (int c = 0; c < 4; c++){
            af0[c]   = *(const bf16x8*)(p1 + c*32);
            af0[4+c] = *(const bf16x8*)(p2 + c*32);
        }
    }
    if (has2){
        int r1 = min(t1*16 + m, N-1);
        const ushort* p1 = A1 + (size_t)r1*FDIM + quad*8;
        const ushort* p2 = A2 + (size_t)r1*FDIM + quad*8;
        #pragma unroll
        for (int c = 0; c < 4; c++){
            af1[c]   = *(const bf16x8*)(p1 + c*32);
            af1[4+c] = *(const bf16x8*)(p2 + c*32);
        }
    }

    f32x4 acc0[NT], acc1[NT];
    #pragma unroll
    for (int nt = 0; nt < NT; nt++){ acc0[nt] = f32x4{0.f,0.f,0.f,0.f}; acc1[nt] = f32x4{0.f,0.f,0.f,0.f}; }

    if (has2){
        #pragma unroll
        for (int kt = 0; kt < 8; kt++)
            #pragma unroll
            for (int nt = 0; nt < NT; nt++){
                bf16x8 bfr = *(const bf16x8*)(WSl + (nt*8+kt)*512);
                acc0[nt] = __builtin_amdgcn_mfma_f32_16x16x32_bf16(af0[kt], bfr, acc0[nt], 0, 0, 0);
                acc1[nt] = __builtin_amdgcn_mfma_f32_16x16x32_bf16(af1[kt], bfr, acc1[nt], 0, 0, 0);
            }
    } else {
        #pragma unroll
        for (int kt = 0; kt < 8; kt++)
            #pragma unroll
            for (int nt = 0; nt < NT; nt++){
                bf16x8 bfr = *(const bf16x8*)(WSl + (nt*8+kt)*512);
                acc0[nt] = __builtin_amdgcn_mfma_f32_16x16x32_bf16(af0[kt], bfr, acc0[nt], 0, 0, 0);
            }
    }

    auto epi = [&](int t, f32x4* acc){
        #pragma unroll
        for (int nt = 0; nt < NT; nt++){
            float b = bias[nt*16 + m];
            acc[nt][0]+=b; acc[nt][1]+=b; acc[nt][2]+=b; acc[nt][3]+=b;
        }
        if (NORM){
            #pragma unroll
            for (int reg = 0; reg < 4; reg++){
                float ss = 0.f;
                #pragma unroll
                for (int nt = 0; nt < NT; nt++) ss += acc[nt][reg]*acc[nt][reg];
                ss += __shfl_xor(ss,1); ss += __shfl_xor(ss,2); ss += __shfl_xor(ss,4); ss += __shfl_xor(ss,8);
                float invn = 1.f / fmaxf(sqrtf(ss), 1e-12f);
                #pragma unroll
                for (int nt = 0; nt < NT; nt++) acc[nt][reg] *= invn;
            }
        }
        if (RELU){
            #pragma unroll
            for (int nt = 0; nt < NT; nt++){
                acc[nt][0]=fmaxf(acc[nt][0],0.f); acc[nt][1]=fmaxf(acc[nt][1],0.f);
                acc[nt][2]=fmaxf(acc[nt][2],0.f); acc[nt][3]=fmaxf(acc[nt][3],0.f);
            }
        }
        #pragma unroll
        for (int reg = 0; reg < 4; reg++){
            int row = t*16 + quad*4 + reg;
            if (row < N){
                if (OUTF32){
                    float* o = (float*)outv + (size_t)row*(NT*16) + m;
                    #pragma unroll
                    for (int nt = 0; nt < NT; nt++) o[nt*16] = acc[nt][reg];
                } else {
                    ushort* o = (ushort*)outv + (size_t)row*(NT*16) + m;
                    #pragma unroll
                    for (int nt = 0; nt < NT; nt++) o[nt*16] = f2bf(acc[nt][reg]);
                    if (FP8OUT){
                        unsigned char* o8 = out8 + (size_t)row*(NT*16) + m;
                        #pragma unroll
                        for (int nt = 0; nt < NT; nt++) o8[nt*16] = f2fp8(acc[nt][reg]);
                    }
                }
            }
        }
    };
    epi(t0, acc0);
    if (has2) epi(t1, acc1);
}

// ---------------- launch ----------------

extern "C" void kernel_launch(void* const* d_in, const int* in_sizes, int n_in,
                              void* d_out, int out_size, void* d_ws, size_t ws_size,
                              hipStream_t stream)
{
    const float* x    = (const float*)d_in[0];
    const int*   ei   = (const int*)  d_in[1];
    const float* W1_l = (const float*)d_in[2];
    const float* b1_l = (const float*)d_in[3];
    const float* W1_r = (const float*)d_in[4];
    const float* Wl1  = (const float*)d_in[5];
    const float* bl1  = (const float*)d_in[6];
    const float* W2_l = (const float*)d_in[7];
    const float* b2_l = (const float*)d_in[8];
    const float* W2_r = (const float*)d_in[9];
    float* out = (float*)d_out;

    const int N = in_sizes[0] / FDIM;   // 50000
    const int E = in_sizes[1] / 2;      // 800000

    const int* src = ei;
    const int* dst = ei + E;

    char* p = (char*)d_ws;
    auto carve = [&](size_t bytes) -> void* {
        void* r = (void*)p;
        p += (bytes + 255) & ~(size_t)255;
        return r;
    };

    const int SB  = 256;                         // scatter blocks (scanA scans over this dim)
    const int ESB = (E + SB - 1) / SB;           // 3125 edges per block
    const int NB  = (N + BWD - 1) >> BSH;        // 1563 buckets of 32 nodes

    int*           hist    = (int*)     carve((size_t)SB * NB * 4);
    int*           base    = (int*)     carve((size_t)SB * NB * 4);
    int*           bktcnt  = (int*)     carve((size_t)NB * 4);
    unsigned*      recs    = (unsigned*)carve((size_t)NB * CAPB * 4);
    ushort*        xb      = (ushort*)  carve((size_t)N * FDIM * 2);
    ushort*        hb      = (ushort*)  carve((size_t)N * FDIM * 2);
    ushort*        aggb    = (ushort*)  carve((size_t)N * FDIM * 2);
    unsigned char* x8      = (unsigned char*)carve((size_t)(N + 1) * FDIM);  // +1 dummy row
    unsigned char* h8      = (unsigned char*)carve((size_t)(N + 1) * FDIM);  // +1 dummy row
    ushort*        Wf1     = (ushort*)  carve((size_t)32768 * 2);
    ushort*        Wfm     = (ushort*)  carve((size_t)32768 * 2);
    ushort*        Wf2     = (ushort*)  carve((size_t)16384 * 2);

    const int gCast = (N * FDIM / 4 + 255) / 256;     // 6250
    const int gScan = (NB + SAB - 1) / SAB;           // 98
    const int TILES = (N + 15) / 16;                  // 3125
    const int gLin  = 512;                            // 2048 wave slots, 2 tiles/wave

    // pass 1: bucket histograms | x->bf16+fp8 | weight swizzle | dummy-row zero (fused)
    k_pass1<<<SB + gCast + 320 + 1, 256, 0, stream>>>(dst, hist, E, ESB, NB, SB,
                                                      x, xb, x8, h8, N*FDIM, gCast,
                                                      W1_l, W1_r, Wl1, W2_l, W2_r, Wf1, Wfm, Wf2);
    k_scanA<<<gScan, 256, 0, stream>>>(hist, base, bktcnt, NB);
    k_scatter<<<SB, 256, 0, stream>>>(dst, src, base, recs, E, ESB, NB);

    // layer 1 + mid (fused): h = relu([x | relu(norm([agg(x)|x]W1^T+b1))] Wl1^T + bl1)
    k_agg8<<<NB, 256, 0, stream>>>(x8, recs, bktcnt, dst, src, E, aggb, N);
    k_lin12<<<gLin, 256, 0, stream>>>(aggb, xb, Wf1, Wfm, b1_l, bl1, hb, h8, N, TILES);

    // layer 2: out = norm([agg(h)|h] @ W2^T + b2)  (fp32 out)
    k_agg8<<<NB, 256, 0, stream>>>(h8, recs, bktcnt, dst, src, E, aggb, N);
    k_lin<4, true,  false, true,  false><<<gLin, 256, 0, stream>>>(aggb, hb, Wf2, b2_l, out, nullptr, N, TILES);
}

// Round 6
// 209.158 us; speedup vs baseline: 1.0367x; 1.0367x over previous
//
#include <hip/hip_runtime.h>
#include <hip/hip_bf16.h>

constexpr int FDIM  = 128;
constexpr int BSH   = 5;      // 32 nodes per bucket
constexpr int BWD   = 32;
constexpr int NBMAX = 2048;   // supports N <= 65536 (N = 50000)
constexpr int CAP   = 3072;   // per-bucket LDS record capacity in k_agg8 (incl. padding)
constexpr int CAPB  = 2048;   // fixed per-bucket global record capacity (mean 512, sd ~23)
constexpr int SAB   = 16;     // buckets per scanA block

typedef __attribute__((ext_vector_type(8))) short bf16x8;   // 8 bf16 = 4 VGPRs
typedef __attribute__((ext_vector_type(4))) float f32x4;
typedef __attribute__((ext_vector_type(2))) float f32x2;

static __device__ __forceinline__ ushort f2bf(float f){
    union { float f; unsigned u; } v; v.f = f;
    unsigned r = v.u + 0x7fffu + ((v.u >> 16) & 1u);   // RNE
    return (ushort)(r >> 16);
}
static __device__ __forceinline__ unsigned char f2fp8(float f){
    return (unsigned char)(__builtin_amdgcn_cvt_pk_fp8_f32(f, f, 0, false) & 0xff);
}

// ---------------- pass 1 (fused): bucket histogram | x cast | weight swizzle | dummy-row zero ----------------

__global__ __launch_bounds__(256) void k_pass1(
    const int* __restrict__ dst, int* __restrict__ hist,
    int E, int ESB, int NB, int SB,
    const float* __restrict__ xsrc, ushort* __restrict__ xb,
    unsigned char* __restrict__ x8, unsigned char* __restrict__ h8, int nx, int gC,
    const float* __restrict__ W1_l, const float* __restrict__ W1_r,
    const float* __restrict__ Wl1,
    const float* __restrict__ W2_l, const float* __restrict__ W2_r,
    ushort* __restrict__ Wf1, ushort* __restrict__ Wfm, ushort* __restrict__ Wf2)
{
    const int b = (int)blockIdx.x;
    const int t = (int)threadIdx.x;
    if (b < SB){
        __shared__ int lh[NBMAX];
        for (int i = t; i < NB; i += 256) lh[i] = 0;
        __syncthreads();
        const int e1 = min(E, (b + 1) * ESB);
        for (int e = b * ESB + t; e < e1; e += 256)
            atomicAdd(&lh[dst[e] >> BSH], 1);                 // LDS atomic only
        __syncthreads();
        for (int i = t; i < NB; i += 256) hist[(size_t)b * NB + i] = lh[i];
    } else if (b < SB + gC){
        int i4 = ((b - SB) * 256 + t) * 4;
        if (i4 < nx){
            float4 v = *(const float4*)(xsrc + i4);
            ushort4 o; o.x = f2bf(v.x); o.y = f2bf(v.y); o.z = f2bf(v.z); o.w = f2bf(v.w);
            *(ushort4*)(xb + i4) = o;
            unsigned w = __builtin_amdgcn_cvt_pk_fp8_f32(v.x, v.y, 0, false);
            w = (unsigned)__builtin_amdgcn_cvt_pk_fp8_f32(v.z, v.w, (int)w, true);
            *(unsigned*)(x8 + i4) = w;
        }
    } else if (b < SB + gC + 320){
        // weight swizzle into MFMA fragment order:
        // Wf[((nt*8+kt)*64 + lane)*8 + j] = W[nt*16 + (lane&15)][kt*32 + (lane>>4)*8 + j]
        int i = (b - SB - gC) * 256 + t;                      // 320 blocks -> 81920 ushorts
        int f; ushort* dstp; int which;
        if (i < 32768){ f = i;          dstp = Wf1; which = 0; }
        else if (i < 65536){ f = i - 32768; dstp = Wfm; which = 1; }
        else { f = i - 65536; dstp = Wf2; which = 2; }
        int j    = f & 7;
        int lane = (f >> 3) & 63;
        int q    = f >> 9;
        int kt = q & 7, nt = q >> 3;
        int n = nt * 16 + (lane & 15);
        int k = kt * 32 + (lane >> 4) * 8 + j;
        float v;
        if (which == 0)      v = (k < 128) ? W1_l[(size_t)n * 128 + k] : W1_r[(size_t)n * 128 + (k - 128)];
        else if (which == 1) v = Wl1[(size_t)n * 256 + k];
        else                 v = (k < 128) ? W2_l[(size_t)n * 128 + k] : W2_r[(size_t)n * 128 + (k - 128)];
        dstp[f] = f2bf(v);
    } else {
        // zero the dummy row (index N) of both fp8 feature buffers
        if (t < 8)       *(uint4*)(x8 + (size_t)nx + t*16)      = make_uint4(0,0,0,0);
        else if (t < 16) *(uint4*)(h8 + (size_t)nx + (t-8)*16)  = make_uint4(0,0,0,0);
    }
}

// ---------------- scanA (tiled): per bucket, exclusive scan of hist over 256 scatter blocks ----------------

__global__ __launch_bounds__(256) void k_scanA(const int* __restrict__ hist, int* __restrict__ base,
                                               int* __restrict__ bktcnt, int NB)
{
    __shared__ int T[256][SAB + 1];
    __shared__ int psum[16][SAB];
    const int t = (int)threadIdx.x;
    const int b0 = (int)blockIdx.x * SAB;
    const int cl = t & (SAB - 1);
    const int rt = t >> 4;
    for (int it = 0; it < 16; it++){
        const int row = it * 16 + rt;
        T[row][cl] = (b0 + cl < NB) ? hist[(size_t)row * NB + b0 + cl] : 0;
    }
    __syncthreads();
    const int c = t & (SAB - 1), seg = t >> 4;
    int s = 0;
    #pragma unroll
    for (int i = 0; i < 16; i++) s += T[seg * 16 + i][c];
    psum[seg][c] = s;
    __syncthreads();
    int off = 0;
    #pragma unroll
    for (int s2 = 0; s2 < 16; s2++){ int v = psum[s2][c]; if (s2 < seg) off += v; }
    int run = off;
    #pragma unroll
    for (int i = 0; i < 16; i++){
        const int idx = seg * 16 + i;
        const int v = T[idx][c];
        T[idx][c] = run;
        run += v;
    }
    if (seg == 15 && b0 + c < NB) bktcnt[b0 + c] = run;
    __syncthreads();
    for (int it = 0; it < 16; it++){
        const int row = it * 16 + rt;
        if (b0 + cl < NB) base[(size_t)row * NB + b0 + cl] = T[row][cl];
    }
}

// ---------------- scatter: bucket-sort edges; rec = (dloc<<24) | src*FDIM (premultiplied payload) ----------------
__global__ __launch_bounds__(256) void k_scatter(
    const int* __restrict__ dst, const int* __restrict__ src,
    const int* __restrict__ base,
    unsigned* __restrict__ recs, int E, int ESB, int NB)
{
    __shared__ int gbase[NBMAX];
    __shared__ int h2[NBMAX];
    const int h = (int)blockIdx.x;
    for (int i = (int)threadIdx.x; i < NB; i += 256){
        gbase[i] = base[(size_t)h * NB + i];
        h2[i] = 0;
    }
    __syncthreads();
    const int e1 = min(E, (h + 1) * ESB);
    for (int e = h * ESB + (int)threadIdx.x; e < e1; e += 256){
        const int d = dst[e], s = src[e];
        const int bk = d >> BSH;
        const int r  = atomicAdd(&h2[bk], 1);     // LDS atomic
        const int pos = gbase[bk] + r;
        if (pos < CAPB)                           // overflow edges handled by agg fallback
            recs[(size_t)bk * CAPB + pos] = ((unsigned)(d & (BWD - 1)) << 24) | ((unsigned)s * FDIM);
    }
}

// ---------------- mean aggregation over fp8 features ----------------
// One block per 32-node bucket. Counting-sort to LDS (segments padded to x4 with dummy recs ->
// maskless gather). Each wave processes TWO nodes interleaved: 8 gather loads in flight.

__global__ __launch_bounds__(256) void k_agg8(
    const unsigned char* __restrict__ feat8, const unsigned* __restrict__ recs,
    const int* __restrict__ bktcnt,
    const int* __restrict__ dstg, const int* __restrict__ srcg, int E,
    ushort* __restrict__ agg, int N)
{
    __shared__ unsigned lrec[CAP];
    __shared__ int ldeg[BWD], loffp[BWD + 1], lpos[BWD];

    const int b = (int)blockIdx.x;
    const int t = (int)threadIdx.x;
    const int wave = t >> 6, lane = t & 63;
    const int grp = lane >> 4, sub = lane & 15;
    const int subo = sub * 8;
    const int cnt = bktcnt[b];
    const unsigned* brec = recs + (size_t)b * CAPB;

    if (t < BWD){ ldeg[t] = 0; lpos[t] = 0; }
    __syncthreads();

    auto writeout = [&](int node, int d, f32x2 a01, f32x2 a23, f32x2 a45, f32x2 a67){
        float v0=a01.x,v1=a01.y,v2=a23.x,v3=a23.y,v4=a45.x,v5=a45.y,v6=a67.x,v7=a67.y;
        v0 += __shfl_xor(v0,16); v1 += __shfl_xor(v1,16); v2 += __shfl_xor(v2,16); v3 += __shfl_xor(v3,16);
        v4 += __shfl_xor(v4,16); v5 += __shfl_xor(v5,16); v6 += __shfl_xor(v6,16); v7 += __shfl_xor(v7,16);
        v0 += __shfl_xor(v0,32); v1 += __shfl_xor(v1,32); v2 += __shfl_xor(v2,32); v3 += __shfl_xor(v3,32);
        v4 += __shfl_xor(v4,32); v5 += __shfl_xor(v5,32); v6 += __shfl_xor(v6,32); v7 += __shfl_xor(v7,32);
        if (grp == 0){
            float inv = 1.f / (float)(d > 1 ? d : 1);
            uint4 r;
            r.x = (unsigned)f2bf(v0*inv) | ((unsigned)f2bf(v1*inv) << 16);
            r.y = (unsigned)f2bf(v2*inv) | ((unsigned)f2bf(v3*inv) << 16);
            r.z = (unsigned)f2bf(v4*inv) | ((unsigned)f2bf(v5*inv) << 16);
            r.w = (unsigned)f2bf(v6*inv) | ((unsigned)f2bf(v7*inv) << 16);
            *(uint4*)(agg + (size_t)node*FDIM + subo) = r;
        }
    };

    if (cnt <= CAPB){
        // ---- counting sort with per-node padding to x4 ----
        for (int i = t; i < cnt; i += 256) atomicAdd(&ldeg[(brec[i] >> 24) & (BWD-1)], 1);
        __syncthreads();
        if (t == 0){
            int r = 0;
            #pragma unroll
            for (int j = 0; j < BWD; j++){ loffp[j] = r; r += (ldeg[j] + 3) & ~3; }
            loffp[BWD] = r;               // <= cnt + 96 < CAP always
        }
        __syncthreads();
        for (int i = t; i < cnt; i += 256){
            const unsigned rec = brec[i];
            const int dl = (rec >> 24) & (BWD-1);
            lrec[loffp[dl] + atomicAdd(&lpos[dl], 1)] = rec;
        }
        if (t < BWD){                     // pad slots -> dummy row N (zeroed fp8)
            const int de = (ldeg[t] + 3) & ~3;
            for (int r = ldeg[t]; r < de; r++) lrec[loffp[t] + r] = (unsigned)N * FDIM;
        }
        __syncthreads();

        // ---- two-node interleaved maskless gather (8 loads in flight per wave) ----
        for (int np = wave*2; np < BWD; np += 8){
            const int nodeA = b*BWD + np, nodeB = nodeA + 1;
            const bool vA = nodeA < N, vB = nodeB < N;
            const int oA = loffp[np],   dA = vA ? ldeg[np]   : 0;
            const int oB = loffp[np+1], dB = vB ? ldeg[np+1] : 0;
            const int itA = (dA + 3) >> 2, itB = (dB + 3) >> 2;

            f32x2 A01{0.f,0.f}, A23{0.f,0.f}, A45{0.f,0.f}, A67{0.f,0.f};
            f32x2 B01{0.f,0.f}, B23{0.f,0.f}, B45{0.f,0.f}, B67{0.f,0.f};
            auto accA = [&](uint2 raw){
                A01 += __builtin_amdgcn_cvt_pk_f32_fp8((int)raw.x, false);
                A23 += __builtin_amdgcn_cvt_pk_f32_fp8((int)raw.x, true);
                A45 += __builtin_amdgcn_cvt_pk_f32_fp8((int)raw.y, false);
                A67 += __builtin_amdgcn_cvt_pk_f32_fp8((int)raw.y, true);
            };
            auto accB = [&](uint2 raw){
                B01 += __builtin_amdgcn_cvt_pk_f32_fp8((int)raw.x, false);
                B23 += __builtin_amdgcn_cvt_pk_f32_fp8((int)raw.x, true);
                B45 += __builtin_amdgcn_cvt_pk_f32_fp8((int)raw.y, false);
                B67 += __builtin_amdgcn_cvt_pk_f32_fp8((int)raw.y, true);
            };

            const int jc = min(itA, itB);
            int j = 0;
            for (; j + 2 <= jc; j += 2){
                const unsigned ra0 = lrec[oA + (j+0)*4 + grp];
                const unsigned rb0 = lrec[oB + (j+0)*4 + grp];
                const unsigned ra1 = lrec[oA + (j+1)*4 + grp];
                const unsigned rb1 = lrec[oB + (j+1)*4 + grp];
                uint2 va0 = *(const uint2*)(feat8 + (ra0 & 0xFFFFFFu) + subo);
                uint2 vb0 = *(const uint2*)(feat8 + (rb0 & 0xFFFFFFu) + subo);
                uint2 va1 = *(const uint2*)(feat8 + (ra1 & 0xFFFFFFu) + subo);
                uint2 vb1 = *(const uint2*)(feat8 + (rb1 & 0xFFFFFFu) + subo);
                accA(va0); accB(vb0); accA(va1); accB(vb1);
            }
            for (; j < jc; j++){
                const unsigned ra = lrec[oA + j*4 + grp];
                const unsigned rb = lrec[oB + j*4 + grp];
                uint2 va = *(const uint2*)(feat8 + (ra & 0xFFFFFFu) + subo);
                uint2 vb = *(const uint2*)(feat8 + (rb & 0xFFFFFFu) + subo);
                accA(va); accB(vb);
            }
            for (int ja = jc; ja < itA; ja++){
                const unsigned ra = lrec[oA + ja*4 + grp];
                uint2 va = *(const uint2*)(feat8 + (ra & 0xFFFFFFu) + subo);
                accA(va);
            }
            for (int jb = jc; jb < itB; jb++){
                const unsigned rb = lrec[oB + jb*4 + grp];
                uint2 vb = *(const uint2*)(feat8 + (rb & 0xFFFFFFu) + subo);
                accB(vb);
            }
            if (vA) writeout(nodeA, dA, A01, A23, A45, A67);
            if (vB) writeout(nodeB, dB, B01, B23, B45, B67);
        }
    } else {
        // ---- fallback (bucket overflow; O(E) rescan of the raw edge list; never triggered here) ----
        for (int nl = wave; nl < BWD; nl += 4){
            const int node = b*BWD + nl;
            if (node >= N) break;
            f32x2 a01{0.f,0.f}, a23{0.f,0.f}, a45{0.f,0.f}, a67{0.f,0.f};
            int d = 0;
            for (int e = 0; e < E; e++){
                if (dstg[e] == node){
                    d++;
                    if (grp == 0){
                        uint2 raw = *(const uint2*)(feat8 + (size_t)srcg[e]*FDIM + subo);
                        a01 += __builtin_amdgcn_cvt_pk_f32_fp8((int)raw.x, false);
                        a23 += __builtin_amdgcn_cvt_pk_f32_fp8((int)raw.x, true);
                        a45 += __builtin_amdgcn_cvt_pk_f32_fp8((int)raw.y, false);
                        a67 += __builtin_amdgcn_cvt_pk_f32_fp8((int)raw.y, true);
                    }
                }
            }
            writeout(node, d, a01, a23, a45, a67);
        }
    }
}

// ---------------- fused lin1 + mid-lin (two-phase LDS weights) ----------------
// h1 = relu(norm([agg|x] @ W1^T + b1)) never touches HBM; mid: h = relu([x|h1] @ Wl1^T + bl1).
// Phase 1: Wf1 staged in 64 KB LDS -> GEMM1 from ds_read (fast path, as k_lin).
// Between phases: h1 transpose via wave-private sub-regions of the SAME LDS (W1 dead by then).
// Phase 2: Wfm staged into same LDS -> GEMM2. Barriers guard each reuse.

__global__ __launch_bounds__(256) void k_lin12(
    const ushort* __restrict__ Agg, const ushort* __restrict__ Xb,
    const ushort* __restrict__ Wf1, const ushort* __restrict__ Wfm,
    const float* __restrict__ b1, const float* __restrict__ bm,
    ushort* __restrict__ hb, unsigned char* __restrict__ h8, int N, int TILES)
{
    __shared__ __align__(16) ushort WS[32768];        // 64 KB: W1 | transpose scratch | Wm

    const int wave = threadIdx.x >> 6, lane = threadIdx.x & 63;
    const int m = lane & 15, quad = lane >> 4;
    const ushort* WSl = WS + lane*8;                  // frag (nt,kt) at + (nt*8+kt)*512

    const int g  = (int)blockIdx.x*4 + wave;          // 0..2047
    const int t0 = g, t1 = g + 2048;
    const bool has2 = (t1 < TILES);

    // ---- A-frag loads issued first (overlap with weight staging) ----
    bf16x8 aA0[4], aX0[4], aA1[4], aX1[4];
    {
        const int r0 = min(t0*16 + m, N-1);
        const ushort* p1 = Agg + (size_t)r0*FDIM + quad*8;
        const ushort* p2 = Xb  + (size_t)r0*FDIM + quad*8;
        #pragma unroll
        for (int c = 0; c < 4; c++){
            aA0[c] = *(const bf16x8*)(p1 + c*32);
            aX0[c] = *(const bf16x8*)(p2 + c*32);
        }
    }
    if (has2){
        const int r1 = min(t1*16 + m, N-1);
        const ushort* p1 = Agg + (size_t)r1*FDIM + quad*8;
        const ushort* p2 = Xb  + (size_t)r1*FDIM + quad*8;
        #pragma unroll
        for (int c = 0; c < 4; c++){
            aA1[c] = *(const bf16x8*)(p1 + c*32);
            aX1[c] = *(const bf16x8*)(p2 + c*32);
        }
    }

    // ---- stage Wf1 (64 KB) ----
    {
        const uint4* w1 = (const uint4*)Wf1;
        uint4* wd = (uint4*)WS;
        for (int i = (int)threadIdx.x; i < 4096; i += 256) wd[i] = w1[i];
    }
    __syncthreads();

    // ---- GEMM1: [agg|x] @ W1^T from LDS ----
    f32x4 acc0[8], acc1[8];
    #pragma unroll
    for (int nt = 0; nt < 8; nt++){ acc0[nt] = f32x4{0.f,0.f,0.f,0.f}; acc1[nt] = f32x4{0.f,0.f,0.f,0.f}; }
    if (has2){
        #pragma unroll
        for (int kt = 0; kt < 8; kt++){
            bf16x8 a0 = (kt < 4) ? aA0[kt] : aX0[kt-4];
            bf16x8 a1 = (kt < 4) ? aA1[kt] : aX1[kt-4];
            #pragma unroll
            for (int nt = 0; nt < 8; nt++){
                bf16x8 w = *(const bf16x8*)(WSl + (nt*8+kt)*512);
                acc0[nt] = __builtin_amdgcn_mfma_f32_16x16x32_bf16(a0, w, acc0[nt], 0, 0, 0);
                acc1[nt] = __builtin_amdgcn_mfma_f32_16x16x32_bf16(a1, w, acc1[nt], 0, 0, 0);
            }
        }
    } else {
        #pragma unroll
        for (int kt = 0; kt < 8; kt++){
            bf16x8 a0 = (kt < 4) ? aA0[kt] : aX0[kt-4];
            #pragma unroll
            for (int nt = 0; nt < 8; nt++){
                bf16x8 w = *(const bf16x8*)(WSl + (nt*8+kt)*512);
                acc0[nt] = __builtin_amdgcn_mfma_f32_16x16x32_bf16(a0, w, acc0[nt], 0, 0, 0);
            }
        }
    }
    __syncthreads();          // all waves done reading W1 -> LDS reusable for transpose

    // ---- epi1: bias + L2 row-norm + relu ----
    auto epi1 = [&](f32x4* acc){
        #pragma unroll
        for (int nt = 0; nt < 8; nt++){
            float bb = b1[nt*16 + m];
            acc[nt][0]+=bb; acc[nt][1]+=bb; acc[nt][2]+=bb; acc[nt][3]+=bb;
        }
        #pragma unroll
        for (int reg = 0; reg < 4; reg++){
            float ss = 0.f;
            #pragma unroll
            for (int nt = 0; nt < 8; nt++) ss += acc[nt][reg]*acc[nt][reg];
            ss += __shfl_xor(ss,1); ss += __shfl_xor(ss,2); ss += __shfl_xor(ss,4); ss += __shfl_xor(ss,8);
            float invn = 1.f / fmaxf(sqrtf(ss), 1e-12f);
            #pragma unroll
            for (int nt = 0; nt < 8; nt++) acc[nt][reg] = fmaxf(acc[nt][reg]*invn, 0.f);
        }
    };
    // ---- transpose h1 tile (C layout -> A-frag layout) via wave-private XOR-swizzled LDS ----
    auto transpose = [&](const f32x4* acc, ushort* hTw, bf16x8* afH){
        #pragma unroll
        for (int nt = 0; nt < 8; nt++)
            #pragma unroll
            for (int reg = 0; reg < 4; reg++){
                const int row = quad*4 + reg;
                hTw[(row*128 + nt*16 + m) ^ ((row & 7) << 3)] = f2bf(acc[nt][reg]);
            }
        #pragma unroll
        for (int c = 0; c < 4; c++)
            afH[c] = *(const bf16x8*)&hTw[(m*128 + quad*8 + c*32) ^ ((m & 7) << 3)];
    };

    bf16x8 aH0[4], aH1[4];
    ushort* hTw = WS + wave*4096;      // wave-private 8 KB region (2 tiles x 2048 ushorts)
    epi1(acc0);
    transpose(acc0, hTw, aH0);
    if (has2){
        epi1(acc1);
        transpose(acc1, hTw + 2048, aH1);
    }
    __syncthreads();          // all transpose reads done -> LDS reusable for Wm

    // ---- stage Wfm (64 KB) ----
    {
        const uint4* wm = (const uint4*)Wfm;
        uint4* wd = (uint4*)WS;
        for (int i = (int)threadIdx.x; i < 4096; i += 256) wd[i] = wm[i];
    }
    __syncthreads();

    // ---- GEMM2: [x|h1] @ Wl1^T from LDS ----
    f32x4 am0[8], am1[8];
    #pragma unroll
    for (int nt = 0; nt < 8; nt++){ am0[nt] = f32x4{0.f,0.f,0.f,0.f}; am1[nt] = f32x4{0.f,0.f,0.f,0.f}; }
    if (has2){
        #pragma unroll
        for (int kt = 0; kt < 8; kt++){
            bf16x8 a0 = (kt < 4) ? aX0[kt] : aH0[kt-4];
            bf16x8 a1 = (kt < 4) ? aX1[kt] : aH1[kt-4];
            #pragma unroll
            for (int nt = 0; nt < 8; nt++){
                bf16x8 w = *(const bf16x8*)(WSl + (nt*8+kt)*512);
                am0[nt] = __builtin_amdgcn_mfma_f32_16x16x32_bf16(a0, w, am0[nt], 0, 0, 0);
                am1[nt] = __builtin_amdgcn_mfma_f32_16x16x32_bf16(a1, w, am1[nt], 0, 0, 0);
            }
        }
    } else {
        #pragma unroll
        for (int kt = 0; kt < 8; kt++){
            bf16x8 a0 = (kt < 4) ? aX0[kt] : aH0[kt-4];
            #pragma unroll
            for (int nt = 0; nt < 8; nt++){
                bf16x8 w = *(const bf16x8*)(WSl + (nt*8+kt)*512);
                am0[nt] = __builtin_amdgcn_mfma_f32_16x16x32_bf16(a0, w, am0[nt], 0, 0, 0);
            }
        }
    }

    // ---- epi-mid: bias + relu, store hb (bf16) + h8 (fp8) ----
    auto epim = [&](int tt, f32x4* acc){
        #pragma unroll
        for (int nt = 0; nt < 8; nt++){
            float bb = bm[nt*16 + m];
            acc[nt][0]=fmaxf(acc[nt][0]+bb,0.f); acc[nt][1]=fmaxf(acc[nt][1]+bb,0.f);
            acc[nt][2]=fmaxf(acc[nt][2]+bb,0.f); acc[nt][3]=fmaxf(acc[nt][3]+bb,0.f);
        }
        #pragma unroll
        for (int reg = 0; reg < 4; reg++){
            const int row = tt*16 + quad*4 + reg;
            if (row < N){
                ushort* o = hb + (size_t)row*FDIM + m;
                unsigned char* o8 = h8 + (size_t)row*FDIM + m;
                #pragma unroll
                for (int nt = 0; nt < 8; nt++){
                    o[nt*16]  = f2bf(acc[nt][reg]);
                    o8[nt*16] = f2fp8(acc[nt][reg]);
                }
            }
        }
    };
    epim(t0, am0);
    if (has2) epim(t1, am1);
}

// ---------------- LDS-weight linear (layer 2) ----------------

template<int NT, bool NORM, bool RELU, bool OUTF32, bool FP8OUT>
__global__ __launch_bounds__(256) void k_lin(
    const ushort* __restrict__ A1, const ushort* __restrict__ A2,
    const ushort* __restrict__ Wf, const float* __restrict__ bias,
    void* __restrict__ outv, unsigned char* __restrict__ out8, int N, int TILES)
{
    __shared__ __align__(16) ushort WS[NT*8*64*8];   // NT*8 KB
    {
        const uint4* wsrc = (const uint4*)Wf;
        uint4* wdst = (uint4*)WS;
        for (int i = threadIdx.x; i < NT*512; i += 256) wdst[i] = wsrc[i];
    }
    __syncthreads();

    const int wave = threadIdx.x >> 6, lane = threadIdx.x & 63;
    const int m = lane & 15, quad = lane >> 4;
    const ushort* WSl = WS + lane*8;    // frag (nt,kt) at WSl + (nt*8+kt)*512

    const int g  = blockIdx.x*4 + wave;          // 0..2047
    const int t0 = g, t1 = g + 2048;
    const bool has2 = (t1 < TILES);

    bf16x8 af0[8], af1[8];
    {
        int r0 = min(t0*16 + m, N-1);
        const ushort* p1 = A1 + (size_t)r0*FDIM + quad*8;
        const ushort* p2 = A2 + (size_t)r0*FDIM + quad*8;
        #pragma unroll
        for (int c = 0; c < 4; c++){
            af0[c]   = *(const bf16x8*)(p1 + c*32);
            af0[4+c] = *(const bf16x8*)(p2 + c*32);
        }
    }
    if (has2){
        int r1 = min(t1*16 + m, N-1);
        const ushort* p1 = A1 + (size_t)r1*FDIM + quad*8;
        const ushort* p2 = A2 + (size_t)r1*FDIM + quad*8;
        #pragma unroll
        for (int c = 0; c < 4; c++){
            af1[c]   = *(const bf16x8*)(p1 + c*32);
            af1[4+c] = *(const bf16x8*)(p2 + c*32);
        }
    }

    f32x4 acc0[NT], acc1[NT];
    #pragma unroll
    for (int nt = 0; nt < NT; nt++){ acc0[nt] = f32x4{0.f,0.f,0.f,0.f}; acc1[nt] = f32x4{0.f,0.f,0.f,0.f}; }

    if (has2){
        #pragma unroll
        for (int kt = 0; kt < 8; kt++)
            #pragma unroll
            for (int nt = 0; nt < NT; nt++){
                bf16x8 bfr = *(const bf16x8*)(WSl + (nt*8+kt)*512);
                acc0[nt] = __builtin_amdgcn_mfma_f32_16x16x32_bf16(af0[kt], bfr, acc0[nt], 0, 0, 0);
                acc1[nt] = __builtin_amdgcn_mfma_f32_16x16x32_bf16(af1[kt], bfr, acc1[nt], 0, 0, 0);
            }
    } else {
        #pragma unroll
        for (int kt = 0; kt < 8; kt++)
            #pragma unroll
            for (int nt = 0; nt < NT; nt++){
                bf16x8 bfr = *(const bf16x8*)(WSl + (nt*8+kt)*512);
                acc0[nt] = __builtin_amdgcn_mfma_f32_16x16x32_bf16(af0[kt], bfr, acc0[nt], 0, 0, 0);
            }
    }

    auto epi = [&](int t, f32x4* acc){
        #pragma unroll
        for (int nt = 0; nt < NT; nt++){
            float b = bias[nt*16 + m];
            acc[nt][0]+=b; acc[nt][1]+=b; acc[nt][2]+=b; acc[nt][3]+=b;
        }
        if (NORM){
            #pragma unroll
            for (int reg = 0; reg < 4; reg++){
                float ss = 0.f;
                #pragma unroll
                for (int nt = 0; nt < NT; nt++) ss += acc[nt][reg]*acc[nt][reg];
                ss += __shfl_xor(ss,1); ss += __shfl_xor(ss,2); ss += __shfl_xor(ss,4); ss += __shfl_xor(ss,8);
                float invn = 1.f / fmaxf(sqrtf(ss), 1e-12f);
                #pragma unroll
                for (int nt = 0; nt < NT; nt++) acc[nt][reg] *= invn;
            }
        }
        if (RELU){
            #pragma unroll
            for (int nt = 0; nt < NT; nt++){
                acc[nt][0]=fmaxf(acc[nt][0],0.f); acc[nt][1]=fmaxf(acc[nt][1],0.f);
                acc[nt][2]=fmaxf(acc[nt][2],0.f); acc[nt][3]=fmaxf(acc[nt][3],0.f);
            }
        }
        #pragma unroll
        for (int reg = 0; reg < 4; reg++){
            int row = t*16 + quad*4 + reg;
            if (row < N){
                if (OUTF32){
                    float* o = (float*)outv + (size_t)row*(NT*16) + m;
                    #pragma unroll
                    for (int nt = 0; nt < NT; nt++) o[nt*16] = acc[nt][reg];
                } else {
                    ushort* o = (ushort*)outv + (size_t)row*(NT*16) + m;
                    #pragma unroll
                    for (int nt = 0; nt < NT; nt++) o[nt*16] = f2bf(acc[nt][reg]);
                    if (FP8OUT){
                        unsigned char* o8 = out8 + (size_t)row*(NT*16) + m;
                        #pragma unroll
                        for (int nt = 0; nt < NT; nt++) o8[nt*16] = f2fp8(acc[nt][reg]);
                    }
                }
            }
        }
    };
    epi(t0, acc0);
    if (has2) epi(t1, acc1);
}

// ---------------- launch ----------------

extern "C" void kernel_launch(void* const* d_in, const int* in_sizes, int n_in,
                              void* d_out, int out_size, void* d_ws, size_t ws_size,
                              hipStream_t stream)
{
    const float* x    = (const float*)d_in[0];
    const int*   ei   = (const int*)  d_in[1];
    const float* W1_l = (const float*)d_in[2];
    const float* b1_l = (const float*)d_in[3];
    const float* W1_r = (const float*)d_in[4];
    const float* Wl1  = (const float*)d_in[5];
    const float* bl1  = (const float*)d_in[6];
    const float* W2_l = (const float*)d_in[7];
    const float* b2_l = (const float*)d_in[8];
    const float* W2_r = (const float*)d_in[9];
    float* out = (float*)d_out;

    const int N = in_sizes[0] / FDIM;   // 50000
    const int E = in_sizes[1] / 2;      // 800000

    const int* src = ei;
    const int* dst = ei + E;

    char* p = (char*)d_ws;
    auto carve = [&](size_t bytes) -> void* {
        void* r = (void*)p;
        p += (bytes + 255) & ~(size_t)255;
        return r;
    };

    const int SB  = 256;                         // scatter blocks (scanA scans over this dim)
    const int ESB = (E + SB - 1) / SB;           // 3125 edges per block
    const int NB  = (N + BWD - 1) >> BSH;        // 1563 buckets of 32 nodes

    int*           hist    = (int*)     carve((size_t)SB * NB * 4);
    int*           base    = (int*)     carve((size_t)SB * NB * 4);
    int*           bktcnt  = (int*)     carve((size_t)NB * 4);
    unsigned*      recs    = (unsigned*)carve((size_t)NB * CAPB * 4);
    ushort*        xb      = (ushort*)  carve((size_t)N * FDIM * 2);
    ushort*        hb      = (ushort*)  carve((size_t)N * FDIM * 2);
    ushort*        aggb    = (ushort*)  carve((size_t)N * FDIM * 2);
    unsigned char* x8      = (unsigned char*)carve((size_t)(N + 1) * FDIM);  // +1 dummy row
    unsigned char* h8      = (unsigned char*)carve((size_t)(N + 1) * FDIM);  // +1 dummy row
    ushort*        Wf1     = (ushort*)  carve((size_t)32768 * 2);
    ushort*        Wfm     = (ushort*)  carve((size_t)32768 * 2);
    ushort*        Wf2     = (ushort*)  carve((size_t)16384 * 2);

    const int gCast = (N * FDIM / 4 + 255) / 256;     // 6250
    const int gScan = (NB + SAB - 1) / SAB;           // 98
    const int TILES = (N + 15) / 16;                  // 3125
    const int gLin  = 512;                            // 2048 wave slots, 2 tiles/wave

    // pass 1: bucket histograms | x->bf16+fp8 | weight swizzle | dummy-row zero (fused)
    k_pass1<<<SB + gCast + 320 + 1, 256, 0, stream>>>(dst, hist, E, ESB, NB, SB,
                                                      x, xb, x8, h8, N*FDIM, gCast,
                                                      W1_l, W1_r, Wl1, W2_l, W2_r, Wf1, Wfm, Wf2);
    k_scanA<<<gScan, 256, 0, stream>>>(hist, base, bktcnt, NB);
    k_scatter<<<SB, 256, 0, stream>>>(dst, src, base, recs, E, ESB, NB);

    // layer 1 + mid (fused): h = relu([x | relu(norm([agg(x)|x]W1^T+b1))] Wl1^T + bl1)
    k_agg8<<<NB, 256, 0, stream>>>(x8, recs, bktcnt, dst, src, E, aggb, N);
    k_lin12<<<gLin, 256, 0, stream>>>(aggb, xb, Wf1, Wfm, b1_l, bl1, hb, h8, N, TILES);

    // layer 2: out = norm([agg(h)|h] @ W2^T + b2)  (fp32 out)
    k_agg8<<<NB, 256, 0, stream>>>(h8, recs, bktcnt, dst, src, E, aggb, N);
    k_lin<4, true,  false, true,  false><<<gLin, 256, 0, stream>>>(aggb, hb, Wf2, b2_l, out, nullptr, N, TILES);
}